// Round 5
// baseline (838.042 us; speedup 1.0000x reference)
//
#include <hip/hip_runtime.h>

typedef _Float16 half8 __attribute__((ext_vector_type(8)));
typedef _Float16 half4 __attribute__((ext_vector_type(4)));
typedef __fp16 fp16x2 __attribute__((ext_vector_type(2)));
typedef float f32x4 __attribute__((ext_vector_type(4)));

#define SELU_SCALE 1.0507009873554805f
#define SELU_ALPHA 1.6732632423543772f
#define LOG2E 1.4426950408889634f
#define LN2f 0.6931471805599453f
#define CA (SELU_ALPHA * LOG2E)

// ---- LDS: fragment-linear weights (conflict-free ds_read_b64 A-frags) ----
// frag slot = ((mt*KT + kt)*64 + lane)*8 bytes, each slot = half4
#define W1F 0        // [8][2][64]  = 8192 B
#define W2F 8192     // [8][8][64]  = 32768 B
#define W3F 40960    // [2][8][64]  = 8192 B
#define B0O 49152    // 32 f32 (pre-scaled by log2e)
#define B1O 49280    // 128 f32
#define B2O 49792    // 128 f32
#define B3O 50304    // 32 f32
#define LDS_SZ 50432 // ~49.3 KB -> 2 blocks/CU, 16 waves/CU

__device__ __forceinline__ unsigned pk2(float a, float b) {
    union { fp16x2 h; unsigned u; } v;
    v.h = __builtin_amdgcn_cvt_pkrtz(a, b);
    return v.u;
}

// t-domain scaled selu: input t = log2e*x; output = log2e*act(x)
// (log2e folded into producer W,b; ln2*selu_scale folded into consumer W)
__device__ __forceinline__ float actt(float t) {
    float y = __builtin_fmaf(CA, exp2f(t), -CA);
    return t > 0.0f ? t : y;
}

// act + pack D-frag -> x16 B-frag (identical lane layouts)
__device__ __forceinline__ half4 pack4(f32x4 a) {
    union { unsigned u[2]; half4 h; } w;
    w.u[0] = pk2(actt(a[0]), actt(a[1]));
    w.u[1] = pk2(actt(a[2]), actt(a[3]));
    return w.h;
}

extern "C" __global__ void __launch_bounds__(512, 4)
extractor_mlp_kernel(const float* __restrict__ x, const float* __restrict__ y,
                     const float* __restrict__ W0, const float* __restrict__ b0,
                     const float* __restrict__ W1, const float* __restrict__ b1,
                     const float* __restrict__ W2, const float* __restrict__ b2,
                     const float* __restrict__ W3, const float* __restrict__ b3,
                     const float* __restrict__ W4, const float* __restrict__ b4,
                     const float* __restrict__ W5, const float* __restrict__ b5,
                     float* __restrict__ out) {
    __shared__ __align__(16) unsigned char lds[LDS_SZ];
    const int tid = threadIdx.x;
    const int lane = tid & 63;
    const int wave = tid >> 6;
    const int r = lane & 15;
    const int g = lane >> 4;

    // ---------- stage fragment-linear weights (f16, scales folded) ----------
    // x16 A-frag: A[row = mt*16 + (l&15)][k = kt*16 + (l>>4)*4 + e] = W[k][row]
    for (int i = tid; i < 1024; i += 512) {      // W1 [32][128], scale s
        int l = i & 63, kt = (i >> 6) & 1, mt = i >> 7;
        const float* src = W1 + (kt * 16 + (l >> 4) * 4) * 128 + mt * 16 + (l & 15);
        half4 h;
#pragma unroll
        for (int e = 0; e < 4; ++e) h[e] = (_Float16)(src[e * 128] * SELU_SCALE);
        *(half4*)(lds + W1F + i * 8) = h;
    }
    for (int i = tid; i < 4096; i += 512) {      // W2 [128][128], scale s
        int l = i & 63, kt = (i >> 6) & 7, mt = i >> 9;
        const float* src = W2 + (kt * 16 + (l >> 4) * 4) * 128 + mt * 16 + (l & 15);
        half4 h;
#pragma unroll
        for (int e = 0; e < 4; ++e) h[e] = (_Float16)(src[e * 128] * SELU_SCALE);
        *(half4*)(lds + W2F + i * 8) = h;
    }
    for (int i = tid; i < 1024; i += 512) {      // W3 [128][32], scale s
        int l = i & 63, kt = (i >> 6) & 7, mt = i >> 9;
        const float* src = W3 + (kt * 16 + (l >> 4) * 4) * 32 + mt * 16 + (l & 15);
        half4 h;
#pragma unroll
        for (int e = 0; e < 4; ++e) h[e] = (_Float16)(src[e * 32] * SELU_SCALE);
        *(half4*)(lds + W3F + i * 8) = h;
    }
    for (int i = tid; i < 32; i += 512)  ((float*)(lds + B0O))[i] = b0[i] * LOG2E;
    for (int i = tid; i < 128; i += 512) ((float*)(lds + B1O))[i] = b1[i] * LOG2E;
    for (int i = tid; i < 128; i += 512) ((float*)(lds + B2O))[i] = b2[i] * LOG2E;
    for (int i = tid; i < 32; i += 512)  ((float*)(lds + B3O))[i] = b3[i] * LOG2E;

    // ---------- small per-lane constants straight from global ----------
    half8 wa0[2];   // L0 A-frag (x32): k = g*8+e, zero-padded k>=6; scale log2e
#pragma unroll
    for (int mt = 0; mt < 2; ++mt) {
        half8 h;
#pragma unroll
        for (int e = 0; e < 8; ++e) {
            int k = g * 8 + e;
            float v = (k < 6) ? W0[k * 32 + mt * 16 + r] * LOG2E : 0.0f;
            h[e] = (_Float16)v;
        }
        wa0[mt] = h;
    }
    half4 wa4[2];   // L4 A-frag (x16), scale s
#pragma unroll
    for (int kt = 0; kt < 2; ++kt) {
        half4 h;
#pragma unroll
        for (int e = 0; e < 4; ++e)
            h[e] = (_Float16)(W4[(kt * 16 + g * 4 + e) * 16 + r] * SELU_SCALE);
        wa4[kt] = h;
    }
    f32x4 b4v, w5v;
#pragma unroll
    for (int e = 0; e < 4; ++e) {
        b4v[e] = b4[g * 4 + e] * LOG2E;
        w5v[e] = W5[g * 4 + e] * (SELU_SCALE * LN2f);  // ln2 consumes t-domain
    }
    const float b5v = b5[0];

    __syncthreads();   // only barrier: weights ready

    // block = 2048 tokens (divides 65536 -> single image per block)
    const int wbase = blockIdx.x * 2048 + wave * 32;
    const float* xb = x + (blockIdx.x >> 5) * 196608;
    const float* yb = y + (blockIdx.x >> 5) * 196608;
    const int pb = ((blockIdx.x & 31) << 11) + wave * 32 + r;

    float cur[12], nxt[12];
#pragma unroll
    for (int nt = 0; nt < 2; ++nt) {
        cur[nt * 6 + 0] = xb[pb + nt * 16];
        cur[nt * 6 + 1] = xb[65536 + pb + nt * 16];
        cur[nt * 6 + 2] = xb[131072 + pb + nt * 16];
        cur[nt * 6 + 3] = yb[pb + nt * 16];
        cur[nt * 6 + 4] = yb[65536 + pb + nt * 16];
        cur[nt * 6 + 5] = yb[131072 + pb + nt * 16];
    }

    const unsigned char* fbase = lds + lane * 8;   // frag base; rest is imm offsets

#pragma unroll 1
    for (int it = 0; it < 8; ++it) {
        // L0 B-frags for both halves (lanes g>=1 carry junk: A-frag zeros cover)
        half8 hbf[2];
#pragma unroll
        for (int nt = 0; nt < 2; ++nt) {
            union { unsigned u[4]; half8 h; } hu;
            hu.u[0] = pk2(cur[nt * 6 + 0], cur[nt * 6 + 1]);
            hu.u[1] = pk2(cur[nt * 6 + 2], cur[nt * 6 + 3]);
            hu.u[2] = pk2(cur[nt * 6 + 4], cur[nt * 6 + 5]);
            hu.u[3] = 0;
            hbf[nt] = hu.h;
        }
        // prefetch next iter's inputs under this iter's compute
        if (it != 7) {
            const int p = pb + (it + 1) * 256;
#pragma unroll
            for (int nt = 0; nt < 2; ++nt) {
                nxt[nt * 6 + 0] = xb[p + nt * 16];
                nxt[nt * 6 + 1] = xb[65536 + p + nt * 16];
                nxt[nt * 6 + 2] = xb[131072 + p + nt * 16];
                nxt[nt * 6 + 3] = yb[p + nt * 16];
                nxt[nt * 6 + 4] = yb[65536 + p + nt * 16];
                nxt[nt * 6 + 5] = yb[131072 + p + nt * 16];
            }
        }

#pragma unroll
        for (int nt = 0; nt < 2; ++nt) {
            // ---- L0 (6->32, x32): inputs & weights in registers ----
            f32x4 a0[2];
#pragma unroll
            for (int mt = 0; mt < 2; ++mt) {
                a0[mt] = *(const f32x4*)(lds + B0O + (mt * 16 + g * 4) * 4);
                a0[mt] = __builtin_amdgcn_mfma_f32_16x16x32_f16(wa0[mt], hbf[nt], a0[mt], 0, 0, 0);
            }
            half4 p0[2] = { pack4(a0[0]), pack4(a0[1]) };

            // ---- L1 (32->128, x16): B from regs, A from LDS frags ----
            f32x4 a1[8];
#pragma unroll
            for (int mt = 0; mt < 8; ++mt)
                a1[mt] = *(const f32x4*)(lds + B1O + (mt * 16 + g * 4) * 4);
#pragma unroll
            for (int kt = 0; kt < 2; ++kt)
#pragma unroll
                for (int mt = 0; mt < 8; ++mt) {
                    half4 a = *(const half4*)(fbase + W1F + (mt * 2 + kt) * 512);
                    a1[mt] = __builtin_amdgcn_mfma_f32_16x16x16f16(a, p0[kt], a1[mt], 0, 0, 0);
                }
            half4 p1[8];
#pragma unroll
            for (int mt = 0; mt < 8; ++mt) p1[mt] = pack4(a1[mt]);

            // ---- L2 (128->128, x16): all-register handoff ----
            f32x4 a2[8];
#pragma unroll
            for (int mt = 0; mt < 8; ++mt)
                a2[mt] = *(const f32x4*)(lds + B2O + (mt * 16 + g * 4) * 4);
#pragma unroll
            for (int kt = 0; kt < 8; ++kt)
#pragma unroll
                for (int mt = 0; mt < 8; ++mt) {
                    half4 a = *(const half4*)(fbase + W2F + (mt * 8 + kt) * 512);
                    a2[mt] = __builtin_amdgcn_mfma_f32_16x16x16f16(a, p1[kt], a2[mt], 0, 0, 0);
                }
            half4 p2[8];
#pragma unroll
            for (int mt = 0; mt < 8; ++mt) p2[mt] = pack4(a2[mt]);

            // ---- L3 (128->32, x16) ----
            f32x4 a3[2];
#pragma unroll
            for (int mt = 0; mt < 2; ++mt)
                a3[mt] = *(const f32x4*)(lds + B3O + (mt * 16 + g * 4) * 4);
#pragma unroll
            for (int kt = 0; kt < 8; ++kt)
#pragma unroll
                for (int mt = 0; mt < 2; ++mt) {
                    half4 a = *(const half4*)(fbase + W3F + (mt * 8 + kt) * 512);
                    a3[mt] = __builtin_amdgcn_mfma_f32_16x16x16f16(a, p2[kt], a3[mt], 0, 0, 0);
                }
            half4 p3[2] = { pack4(a3[0]), pack4(a3[1]) };

            // ---- L4 (32->16, x16, all-register) ----
            f32x4 a4 = b4v;
#pragma unroll
            for (int kt = 0; kt < 2; ++kt)
                a4 = __builtin_amdgcn_mfma_f32_16x16x16f16(wa4[kt], p3[kt], a4, 0, 0, 0);

            // ---- L5 (16->1): dot + cross-g reduce ----
            float d = 0.0f;
#pragma unroll
            for (int e = 0; e < 4; ++e) d += actt(a4[e]) * w5v[e];
            d += __shfl_xor(d, 16);
            d += __shfl_xor(d, 32);
            const float s = d + b5v;
            if (lane < 16) out[wbase + it * 256 + nt * 16 + lane] = s;
        }

#pragma unroll
        for (int i = 0; i < 12; ++i) cur[i] = nxt[i];
    }
}

extern "C" void kernel_launch(void* const* d_in, const int* in_sizes, int n_in,
                              void* d_out, int out_size, void* d_ws, size_t ws_size,
                              hipStream_t stream) {
    const float* x  = (const float*)d_in[0];
    const float* y  = (const float*)d_in[1];
    const float* W0 = (const float*)d_in[2];
    const float* b0 = (const float*)d_in[3];
    const float* W1 = (const float*)d_in[4];
    const float* b1 = (const float*)d_in[5];
    const float* W2 = (const float*)d_in[6];
    const float* b2 = (const float*)d_in[7];
    const float* W3 = (const float*)d_in[8];
    const float* b3 = (const float*)d_in[9];
    const float* W4 = (const float*)d_in[10];
    const float* b4 = (const float*)d_in[11];
    const float* W5 = (const float*)d_in[12];
    const float* b5 = (const float*)d_in[13];
    float* out = (float*)d_out;

    extractor_mlp_kernel<<<dim3(512), dim3(512), 0, stream>>>(
        x, y, W0, b0, W1, b1, W2, b2, W3, b3, W4, b4, W5, b5, out);
}

// Round 6
// 359.159 us; speedup vs baseline: 2.3333x; 2.3333x over previous
//
#include <hip/hip_runtime.h>

typedef _Float16 half8 __attribute__((ext_vector_type(8)));
typedef _Float16 half4 __attribute__((ext_vector_type(4)));
typedef __fp16 fp16x2 __attribute__((ext_vector_type(2)));
typedef float f32x4 __attribute__((ext_vector_type(4)));

#define SELU_SCALE 1.0507009873554805f
#define SELU_ALPHA 1.6732632423543772f
#define LOG2E 1.4426950408889634f
#define LN2f 0.6931471805599453f
#define CA (SELU_ALPHA * LOG2E)

// ---- LDS: fragment-linear weights (conflict-free ds_read_b64 A-frags) ----
// frag slot = ((mt*KT + kt)*64 + lane)*8 bytes, each slot = half4
#define W1F 0        // [8][2][64]  = 8192 B
#define W2F 8192     // [8][8][64]  = 32768 B
#define W3F 40960    // [2][8][64]  = 8192 B
#define B0O 49152    // 32 f32 (pre-scaled by log2e)
#define B1O 49280    // 128 f32
#define B2O 49792    // 128 f32
#define B3O 50304    // 32 f32
#define LDS_SZ 50432 // ~49.3 KB

__device__ __forceinline__ unsigned pk2(float a, float b) {
    union { fp16x2 h; unsigned u; } v;
    v.h = __builtin_amdgcn_cvt_pkrtz(a, b);
    return v.u;
}

// t-domain scaled selu: input t = log2e*x; output = log2e*act(x)
// (log2e folded into producer W,b; ln2*selu_scale folded into consumer W)
__device__ __forceinline__ float actt(float t) {
    float y = __builtin_fmaf(CA, exp2f(t), -CA);
    return t > 0.0f ? t : y;
}

// act + pack D-frag -> x16 B-frag (identical lane layouts)
__device__ __forceinline__ half4 pack4(f32x4 a) {
    union { unsigned u[2]; half4 h; } w;
    w.u[0] = pk2(actt(a[0]), actt(a[1]));
    w.u[1] = pk2(actt(a[2]), actt(a[3]));
    return w.h;
}

extern "C" __global__ void __launch_bounds__(512, 2)
extractor_mlp_kernel(const float* __restrict__ x, const float* __restrict__ y,
                     const float* __restrict__ W0, const float* __restrict__ b0,
                     const float* __restrict__ W1, const float* __restrict__ b1,
                     const float* __restrict__ W2, const float* __restrict__ b2,
                     const float* __restrict__ W3, const float* __restrict__ b3,
                     const float* __restrict__ W4, const float* __restrict__ b4,
                     const float* __restrict__ W5, const float* __restrict__ b5,
                     float* __restrict__ out) {
    __shared__ __align__(16) unsigned char lds[LDS_SZ];
    const int tid = threadIdx.x;
    const int lane = tid & 63;
    const int wave = tid >> 6;
    const int r = lane & 15;
    const int g = lane >> 4;

    // ---------- stage fragment-linear weights (f16, scales folded) ----------
    // x16 A-frag: A[row = mt*16 + (l&15)][k = kt*16 + (l>>4)*4 + e] = W[k][row]
    for (int i = tid; i < 1024; i += 512) {      // W1 [32][128], scale s
        int l = i & 63, kt = (i >> 6) & 1, mt = i >> 7;
        const float* src = W1 + (kt * 16 + (l >> 4) * 4) * 128 + mt * 16 + (l & 15);
        half4 h;
#pragma unroll
        for (int e = 0; e < 4; ++e) h[e] = (_Float16)(src[e * 128] * SELU_SCALE);
        *(half4*)(lds + W1F + i * 8) = h;
    }
    for (int i = tid; i < 4096; i += 512) {      // W2 [128][128], scale s
        int l = i & 63, kt = (i >> 6) & 7, mt = i >> 9;
        const float* src = W2 + (kt * 16 + (l >> 4) * 4) * 128 + mt * 16 + (l & 15);
        half4 h;
#pragma unroll
        for (int e = 0; e < 4; ++e) h[e] = (_Float16)(src[e * 128] * SELU_SCALE);
        *(half4*)(lds + W2F + i * 8) = h;
    }
    for (int i = tid; i < 1024; i += 512) {      // W3 [128][32], scale s
        int l = i & 63, kt = (i >> 6) & 7, mt = i >> 9;
        const float* src = W3 + (kt * 16 + (l >> 4) * 4) * 32 + mt * 16 + (l & 15);
        half4 h;
#pragma unroll
        for (int e = 0; e < 4; ++e) h[e] = (_Float16)(src[e * 32] * SELU_SCALE);
        *(half4*)(lds + W3F + i * 8) = h;
    }
    for (int i = tid; i < 32; i += 512)  ((float*)(lds + B0O))[i] = b0[i] * LOG2E;
    for (int i = tid; i < 128; i += 512) ((float*)(lds + B1O))[i] = b1[i] * LOG2E;
    for (int i = tid; i < 128; i += 512) ((float*)(lds + B2O))[i] = b2[i] * LOG2E;
    for (int i = tid; i < 32; i += 512)  ((float*)(lds + B3O))[i] = b3[i] * LOG2E;

    // ---------- small per-lane constants straight from global ----------
    half8 wa0[2];   // L0 A-frag (x32): k = g*8+e, zero-padded k>=6; scale log2e
#pragma unroll
    for (int mt = 0; mt < 2; ++mt) {
        half8 h;
#pragma unroll
        for (int e = 0; e < 8; ++e) {
            int k = g * 8 + e;
            float v = (k < 6) ? W0[k * 32 + mt * 16 + r] * LOG2E : 0.0f;
            h[e] = (_Float16)v;
        }
        wa0[mt] = h;
    }
    half4 wa4[2];   // L4 A-frag (x16), scale s
#pragma unroll
    for (int kt = 0; kt < 2; ++kt) {
        half4 h;
#pragma unroll
        for (int e = 0; e < 4; ++e)
            h[e] = (_Float16)(W4[(kt * 16 + g * 4 + e) * 16 + r] * SELU_SCALE);
        wa4[kt] = h;
    }
    f32x4 b4v, w5v;
#pragma unroll
    for (int e = 0; e < 4; ++e) {
        b4v[e] = b4[g * 4 + e] * LOG2E;
        w5v[e] = W5[g * 4 + e] * (SELU_SCALE * LN2f);  // ln2 consumes t-domain
    }
    const float b5v = b5[0];

    __syncthreads();   // only barrier: weights ready

    // block = 2048 tokens (divides 65536 -> single image per block)
    const int wbase = blockIdx.x * 2048 + wave * 32;
    const float* xb = x + (blockIdx.x >> 5) * 196608;
    const float* yb = y + (blockIdx.x >> 5) * 196608;
    const int pb = ((blockIdx.x & 31) << 11) + wave * 32 + r;

    // inputs kept PACKED (f16 pairs): 6 VGPRs per token-half-pair instead of 12
    unsigned cur[6], nxt[6];
#pragma unroll
    for (int nt = 0; nt < 2; ++nt) {
        cur[nt * 3 + 0] = pk2(xb[pb + nt * 16], xb[65536 + pb + nt * 16]);
        cur[nt * 3 + 1] = pk2(xb[131072 + pb + nt * 16], yb[pb + nt * 16]);
        cur[nt * 3 + 2] = pk2(yb[65536 + pb + nt * 16], yb[131072 + pb + nt * 16]);
    }

    const unsigned char* fbase = lds + lane * 8;   // frag base; rest is imm offsets

#pragma unroll 1
    for (int it = 0; it < 8; ++it) {
        // prefetch next iter's inputs (packed immediately) under this iter's compute
        if (it != 7) {
            const int p = pb + (it + 1) * 256;
#pragma unroll
            for (int nt = 0; nt < 2; ++nt) {
                nxt[nt * 3 + 0] = pk2(xb[p + nt * 16], xb[65536 + p + nt * 16]);
                nxt[nt * 3 + 1] = pk2(xb[131072 + p + nt * 16], yb[p + nt * 16]);
                nxt[nt * 3 + 2] = pk2(yb[65536 + p + nt * 16], yb[131072 + p + nt * 16]);
            }
        }

#pragma unroll
        for (int nt = 0; nt < 2; ++nt) {
            // ---- L0 (6->32, x32): inputs & weights in registers ----
            union { unsigned u[4]; half8 h; } hu;
            hu.u[0] = cur[nt * 3 + 0];
            hu.u[1] = cur[nt * 3 + 1];
            hu.u[2] = cur[nt * 3 + 2];
            hu.u[3] = 0;   // lanes g>=1 carry junk anyway: A-frag zeros cover
            f32x4 a0[2];
#pragma unroll
            for (int mt = 0; mt < 2; ++mt) {
                a0[mt] = *(const f32x4*)(lds + B0O + (mt * 16 + g * 4) * 4);
                a0[mt] = __builtin_amdgcn_mfma_f32_16x16x32_f16(wa0[mt], hu.h, a0[mt], 0, 0, 0);
            }
            half4 p0[2] = { pack4(a0[0]), pack4(a0[1]) };

            // ---- L1 (32->128, x16): B from regs, A from LDS frags ----
            f32x4 a1[8];
#pragma unroll
            for (int mt = 0; mt < 8; ++mt)
                a1[mt] = *(const f32x4*)(lds + B1O + (mt * 16 + g * 4) * 4);
#pragma unroll
            for (int kt = 0; kt < 2; ++kt)
#pragma unroll
                for (int mt = 0; mt < 8; ++mt) {
                    half4 a = *(const half4*)(fbase + W1F + (mt * 2 + kt) * 512);
                    a1[mt] = __builtin_amdgcn_mfma_f32_16x16x16f16(a, p0[kt], a1[mt], 0, 0, 0);
                }
            half4 p1[8];
#pragma unroll
            for (int mt = 0; mt < 8; ++mt) p1[mt] = pack4(a1[mt]);

            // ---- L2 (128->128, x16): all-register handoff ----
            f32x4 a2[8];
#pragma unroll
            for (int mt = 0; mt < 8; ++mt)
                a2[mt] = *(const f32x4*)(lds + B2O + (mt * 16 + g * 4) * 4);
#pragma unroll
            for (int kt = 0; kt < 8; ++kt)
#pragma unroll
                for (int mt = 0; mt < 8; ++mt) {
                    half4 a = *(const half4*)(fbase + W2F + (mt * 8 + kt) * 512);
                    a2[mt] = __builtin_amdgcn_mfma_f32_16x16x16f16(a, p1[kt], a2[mt], 0, 0, 0);
                }
            half4 p2[8];
#pragma unroll
            for (int mt = 0; mt < 8; ++mt) p2[mt] = pack4(a2[mt]);

            // ---- L3 (128->32, x16) ----
            f32x4 a3[2];
#pragma unroll
            for (int mt = 0; mt < 2; ++mt)
                a3[mt] = *(const f32x4*)(lds + B3O + (mt * 16 + g * 4) * 4);
#pragma unroll
            for (int kt = 0; kt < 8; ++kt)
#pragma unroll
                for (int mt = 0; mt < 2; ++mt) {
                    half4 a = *(const half4*)(fbase + W3F + (mt * 8 + kt) * 512);
                    a3[mt] = __builtin_amdgcn_mfma_f32_16x16x16f16(a, p2[kt], a3[mt], 0, 0, 0);
                }
            half4 p3[2] = { pack4(a3[0]), pack4(a3[1]) };

            // ---- L4 (32->16, x16, all-register) ----
            f32x4 a4 = b4v;
#pragma unroll
            for (int kt = 0; kt < 2; ++kt)
                a4 = __builtin_amdgcn_mfma_f32_16x16x16f16(wa4[kt], p3[kt], a4, 0, 0, 0);

            // ---- L5 (16->1): dot + cross-g reduce ----
            float d = 0.0f;
#pragma unroll
            for (int e = 0; e < 4; ++e) d += actt(a4[e]) * w5v[e];
            d += __shfl_xor(d, 16);
            d += __shfl_xor(d, 32);
            const float s = d + b5v;
            if (lane < 16) out[wbase + it * 256 + nt * 16 + lane] = s;
        }

#pragma unroll
        for (int i = 0; i < 6; ++i) cur[i] = nxt[i];
    }
}

extern "C" void kernel_launch(void* const* d_in, const int* in_sizes, int n_in,
                              void* d_out, int out_size, void* d_ws, size_t ws_size,
                              hipStream_t stream) {
    const float* x  = (const float*)d_in[0];
    const float* y  = (const float*)d_in[1];
    const float* W0 = (const float*)d_in[2];
    const float* b0 = (const float*)d_in[3];
    const float* W1 = (const float*)d_in[4];
    const float* b1 = (const float*)d_in[5];
    const float* W2 = (const float*)d_in[6];
    const float* b2 = (const float*)d_in[7];
    const float* W3 = (const float*)d_in[8];
    const float* b3 = (const float*)d_in[9];
    const float* W4 = (const float*)d_in[10];
    const float* b4 = (const float*)d_in[11];
    const float* W5 = (const float*)d_in[12];
    const float* b5 = (const float*)d_in[13];
    float* out = (float*)d_out;

    extractor_mlp_kernel<<<dim3(512), dim3(512), 0, stream>>>(
        x, y, W0, b0, W1, b1, W2, b2, W3, b3, W4, b4, W5, b5, out);
}

// Round 7
// 182.436 us; speedup vs baseline: 4.5936x; 1.9687x over previous
//
#include <hip/hip_runtime.h>

typedef _Float16 half8 __attribute__((ext_vector_type(8)));
typedef _Float16 half4 __attribute__((ext_vector_type(4)));
typedef __fp16 fp16x2 __attribute__((ext_vector_type(2)));
typedef float f32x4 __attribute__((ext_vector_type(4)));

#define SELU_SCALE 1.0507009873554805f
#define SELU_ALPHA 1.6732632423543772f
#define LOG2E 1.4426950408889634f
#define LN2f 0.6931471805599453f
#define CA (SELU_ALPHA * LOG2E)

// ---- LDS: fragment-linear weights (conflict-free ds_read_b64 A-frags) ----
// frag slot = ((mt*KT + kt)*64 + lane)*8 bytes, each slot = half4
#define W1F 0        // [8][2][64]  = 8192 B
#define W2F 8192     // [8][8][64]  = 32768 B
#define W3F 40960    // [2][8][64]  = 8192 B
#define B0O 49152    // 32 f32 (pre-scaled by log2e)
#define B1O 49280    // 128 f32
#define B2O 49792    // 128 f32
#define B3O 50304    // 32 f32
#define LDS_SZ 50432 // ~49.3 KB -> 3 blocks/CU possible (151 KB < 160)

__device__ __forceinline__ unsigned pk2(float a, float b) {
    union { fp16x2 h; unsigned u; } v;
    v.h = __builtin_amdgcn_cvt_pkrtz(a, b);
    return v.u;
}

// t-domain scaled selu: input t = log2e*x; output = log2e*act(x)
// (log2e folded into producer W,b; ln2*selu_scale folded into consumer W)
__device__ __forceinline__ float actt(float t) {
    float y = __builtin_fmaf(CA, exp2f(t), -CA);
    return t > 0.0f ? t : y;
}

// act + pack D-frag -> x16 B-frag (identical lane layouts)
__device__ __forceinline__ half4 pack4(f32x4 a) {
    union { unsigned u[2]; half4 h; } w;
    w.u[0] = pk2(actt(a[0]), actt(a[1]));
    w.u[1] = pk2(actt(a[2]), actt(a[3]));
    return w.h;
}

// 256 threads, min 1 block/CU: VGPR cap 512 under EITHER launch_bounds
// semantics -> allocator free to avoid spill (R5/R6 lesson: FETCH_SIZE
// 2.3GB/940MB was scratch traffic from 64/128-VGPR caps).
extern "C" __global__ void __launch_bounds__(256, 1)
extractor_mlp_kernel(const float* __restrict__ x, const float* __restrict__ y,
                     const float* __restrict__ W0, const float* __restrict__ b0,
                     const float* __restrict__ W1, const float* __restrict__ b1,
                     const float* __restrict__ W2, const float* __restrict__ b2,
                     const float* __restrict__ W3, const float* __restrict__ b3,
                     const float* __restrict__ W4, const float* __restrict__ b4,
                     const float* __restrict__ W5, const float* __restrict__ b5,
                     float* __restrict__ out) {
    __shared__ __align__(16) unsigned char lds[LDS_SZ];
    const int tid = threadIdx.x;
    const int lane = tid & 63;
    const int wave = tid >> 6;
    const int r = lane & 15;
    const int g = lane >> 4;

    // ---------- stage fragment-linear weights (f16, scales folded) ----------
    // x16 A-frag: A[row = mt*16 + (l&15)][k = kt*16 + (l>>4)*4 + e] = W[k][row]
    for (int i = tid; i < 1024; i += 256) {      // W1 [32][128], scale s
        int l = i & 63, kt = (i >> 6) & 1, mt = i >> 7;
        const float* src = W1 + (kt * 16 + (l >> 4) * 4) * 128 + mt * 16 + (l & 15);
        half4 h;
#pragma unroll
        for (int e = 0; e < 4; ++e) h[e] = (_Float16)(src[e * 128] * SELU_SCALE);
        *(half4*)(lds + W1F + i * 8) = h;
    }
    for (int i = tid; i < 4096; i += 256) {      // W2 [128][128], scale s
        int l = i & 63, kt = (i >> 6) & 7, mt = i >> 9;
        const float* src = W2 + (kt * 16 + (l >> 4) * 4) * 128 + mt * 16 + (l & 15);
        half4 h;
#pragma unroll
        for (int e = 0; e < 4; ++e) h[e] = (_Float16)(src[e * 128] * SELU_SCALE);
        *(half4*)(lds + W2F + i * 8) = h;
    }
    for (int i = tid; i < 1024; i += 256) {      // W3 [128][32], scale s
        int l = i & 63, kt = (i >> 6) & 7, mt = i >> 9;
        const float* src = W3 + (kt * 16 + (l >> 4) * 4) * 32 + mt * 16 + (l & 15);
        half4 h;
#pragma unroll
        for (int e = 0; e < 4; ++e) h[e] = (_Float16)(src[e * 32] * SELU_SCALE);
        *(half4*)(lds + W3F + i * 8) = h;
    }
    for (int i = tid; i < 32; i += 256)  ((float*)(lds + B0O))[i] = b0[i] * LOG2E;
    for (int i = tid; i < 128; i += 256) ((float*)(lds + B1O))[i] = b1[i] * LOG2E;
    for (int i = tid; i < 128; i += 256) ((float*)(lds + B2O))[i] = b2[i] * LOG2E;
    for (int i = tid; i < 32; i += 256)  ((float*)(lds + B3O))[i] = b3[i] * LOG2E;

    // ---------- small per-lane constants straight from global ----------
    half8 wa0[2];   // L0 A-frag (x32): k = g*8+e, zero-padded k>=6; scale log2e
#pragma unroll
    for (int mt = 0; mt < 2; ++mt) {
        half8 h;
#pragma unroll
        for (int e = 0; e < 8; ++e) {
            int k = g * 8 + e;
            float v = (k < 6) ? W0[k * 32 + mt * 16 + r] * LOG2E : 0.0f;
            h[e] = (_Float16)v;
        }
        wa0[mt] = h;
    }
    half4 wa4[2];   // L4 A-frag (x16), scale s
#pragma unroll
    for (int kt = 0; kt < 2; ++kt) {
        half4 h;
#pragma unroll
        for (int e = 0; e < 4; ++e)
            h[e] = (_Float16)(W4[(kt * 16 + g * 4 + e) * 16 + r] * SELU_SCALE);
        wa4[kt] = h;
    }
    f32x4 b4v, w5v;
#pragma unroll
    for (int e = 0; e < 4; ++e) {
        b4v[e] = b4[g * 4 + e] * LOG2E;
        w5v[e] = W5[g * 4 + e] * (SELU_SCALE * LN2f);  // ln2 consumes t-domain
    }
    const float b5v = b5[0];

    __syncthreads();   // only barrier: weights ready

    // 1024 blocks x 1024 tokens; 64 blocks per image (65536 px)
    const int tbase = blockIdx.x * 1024 + wave * 256;
    const float* xb = x + (blockIdx.x >> 6) * 196608;
    const float* yb = y + (blockIdx.x >> 6) * 196608;
    const int pb = ((blockIdx.x & 63) << 10) + wave * 256 + r;

    // inputs kept PACKED (f16 pairs): 6 VGPRs instead of 12
    unsigned cur[6], nxt[6];
#pragma unroll
    for (int nt = 0; nt < 2; ++nt) {
        cur[nt * 3 + 0] = pk2(xb[pb + nt * 16], xb[65536 + pb + nt * 16]);
        cur[nt * 3 + 1] = pk2(xb[131072 + pb + nt * 16], yb[pb + nt * 16]);
        cur[nt * 3 + 2] = pk2(yb[65536 + pb + nt * 16], yb[131072 + pb + nt * 16]);
    }

    const unsigned char* fbase = lds + lane * 8;   // frag base; rest is imm offsets

#pragma unroll 1
    for (int it = 0; it < 8; ++it) {
        // prefetch next iter's inputs (packed immediately) under this iter's compute
        if (it != 7) {
            const int p = pb + (it + 1) * 32;
#pragma unroll
            for (int nt = 0; nt < 2; ++nt) {
                nxt[nt * 3 + 0] = pk2(xb[p + nt * 16], xb[65536 + p + nt * 16]);
                nxt[nt * 3 + 1] = pk2(xb[131072 + p + nt * 16], yb[p + nt * 16]);
                nxt[nt * 3 + 2] = pk2(yb[65536 + p + nt * 16], yb[131072 + p + nt * 16]);
            }
        }

#pragma unroll
        for (int nt = 0; nt < 2; ++nt) {
            // ---- L0 (6->32, x32): inputs & weights in registers ----
            union { unsigned u[4]; half8 h; } hu;
            hu.u[0] = cur[nt * 3 + 0];
            hu.u[1] = cur[nt * 3 + 1];
            hu.u[2] = cur[nt * 3 + 2];
            hu.u[3] = 0;   // lanes g>=1 carry junk anyway: A-frag zeros cover
            f32x4 a0[2];
#pragma unroll
            for (int mt = 0; mt < 2; ++mt) {
                a0[mt] = *(const f32x4*)(lds + B0O + (mt * 16 + g * 4) * 4);
                a0[mt] = __builtin_amdgcn_mfma_f32_16x16x32_f16(wa0[mt], hu.h, a0[mt], 0, 0, 0);
            }
            half4 p0[2] = { pack4(a0[0]), pack4(a0[1]) };

            // ---- L1 (32->128, x16): B from regs, A from LDS frags ----
            f32x4 a1[8];
#pragma unroll
            for (int mt = 0; mt < 8; ++mt)
                a1[mt] = *(const f32x4*)(lds + B1O + (mt * 16 + g * 4) * 4);
#pragma unroll
            for (int kt = 0; kt < 2; ++kt)
#pragma unroll
                for (int mt = 0; mt < 8; ++mt) {
                    half4 a = *(const half4*)(fbase + W1F + (mt * 2 + kt) * 512);
                    a1[mt] = __builtin_amdgcn_mfma_f32_16x16x16f16(a, p0[kt], a1[mt], 0, 0, 0);
                }
            half4 p1[8];
#pragma unroll
            for (int mt = 0; mt < 8; ++mt) p1[mt] = pack4(a1[mt]);

            // ---- L2 (128->128, x16): all-register handoff ----
            f32x4 a2[8];
#pragma unroll
            for (int mt = 0; mt < 8; ++mt)
                a2[mt] = *(const f32x4*)(lds + B2O + (mt * 16 + g * 4) * 4);
#pragma unroll
            for (int kt = 0; kt < 8; ++kt)
#pragma unroll
                for (int mt = 0; mt < 8; ++mt) {
                    half4 a = *(const half4*)(fbase + W2F + (mt * 8 + kt) * 512);
                    a2[mt] = __builtin_amdgcn_mfma_f32_16x16x16f16(a, p1[kt], a2[mt], 0, 0, 0);
                }
            half4 p2[8];
#pragma unroll
            for (int mt = 0; mt < 8; ++mt) p2[mt] = pack4(a2[mt]);

            // ---- L3 (128->32, x16) ----
            f32x4 a3[2];
#pragma unroll
            for (int mt = 0; mt < 2; ++mt)
                a3[mt] = *(const f32x4*)(lds + B3O + (mt * 16 + g * 4) * 4);
#pragma unroll
            for (int kt = 0; kt < 8; ++kt)
#pragma unroll
                for (int mt = 0; mt < 2; ++mt) {
                    half4 a = *(const half4*)(fbase + W3F + (mt * 8 + kt) * 512);
                    a3[mt] = __builtin_amdgcn_mfma_f32_16x16x16f16(a, p2[kt], a3[mt], 0, 0, 0);
                }
            half4 p3[2] = { pack4(a3[0]), pack4(a3[1]) };

            // ---- L4 (32->16, x16, all-register) ----
            f32x4 a4 = b4v;
#pragma unroll
            for (int kt = 0; kt < 2; ++kt)
                a4 = __builtin_amdgcn_mfma_f32_16x16x16f16(wa4[kt], p3[kt], a4, 0, 0, 0);

            // ---- L5 (16->1): dot + cross-g reduce ----
            float d = 0.0f;
#pragma unroll
            for (int e = 0; e < 4; ++e) d += actt(a4[e]) * w5v[e];
            d += __shfl_xor(d, 16);
            d += __shfl_xor(d, 32);
            const float s = d + b5v;
            if (lane < 16) out[tbase + it * 32 + nt * 16 + lane] = s;
        }

#pragma unroll
        for (int i = 0; i < 6; ++i) cur[i] = nxt[i];
    }
}

extern "C" void kernel_launch(void* const* d_in, const int* in_sizes, int n_in,
                              void* d_out, int out_size, void* d_ws, size_t ws_size,
                              hipStream_t stream) {
    const float* x  = (const float*)d_in[0];
    const float* y  = (const float*)d_in[1];
    const float* W0 = (const float*)d_in[2];
    const float* b0 = (const float*)d_in[3];
    const float* W1 = (const float*)d_in[4];
    const float* b1 = (const float*)d_in[5];
    const float* W2 = (const float*)d_in[6];
    const float* b2 = (const float*)d_in[7];
    const float* W3 = (const float*)d_in[8];
    const float* b3 = (const float*)d_in[9];
    const float* W4 = (const float*)d_in[10];
    const float* b4 = (const float*)d_in[11];
    const float* W5 = (const float*)d_in[12];
    const float* b5 = (const float*)d_in[13];
    float* out = (float*)d_out;

    extractor_mlp_kernel<<<dim3(1024), dim3(256), 0, stream>>>(
        x, y, W0, b0, W1, b1, W2, b2, W3, b3, W4, b4, W5, b5, out);
}